// Round 5
// baseline (508.793 us; speedup 1.0000x reference)
//
#include <hip/hip_runtime.h>
#include <hip/hip_bf16.h>
#include <stdint.h>

// MetaPN: 3-layer per-sample hypernetwork as 3 GEMMs with on-the-fly
// A = x ⊗ pe outer-product structure.  D=256, DT=64, B=4096.
// Round 5: round 4 + FUSED "s_waitcnt vmcnt(N); s_barrier" single-asm barrier
// (plain s_barrier builtin is not a compiler memory fence -> ds_read hoist
// race between waitcnt and barrier; rule #18 class).

typedef unsigned int u32;
typedef unsigned short u16;
typedef __attribute__((ext_vector_type(8))) short short8;
typedef __attribute__((ext_vector_type(4))) short short4v;
typedef __attribute__((ext_vector_type(4))) float f32x4;

#define DEV static __device__ __forceinline__

DEV float b2f(u16 u){ u32 i = ((u32)u)<<16; float f; __builtin_memcpy(&f,&i,4); return f; }
DEV u16 f2b(float f){ __hip_bfloat16 h = __float2bfloat16(f); u16 u; __builtin_memcpy(&u,&h,2); return u; }

DEV void gll16(const void* g, void* l){
  __builtin_amdgcn_global_load_lds((const __attribute__((address_space(1))) u32*)g,
                                   (__attribute__((address_space(3))) u32*)l, 16, 0, 0);
}

// ---------------- prep: pack weights into bf16 K-tiled swizzled layout -------
// Logical B element (k, n), k = kt*64 + g*8 + e  (g,e in 0..7) stored at byte
// kt*N*128 + n*128 + ((g ^ (n&7))<<4) + e*2.  Swizzle baked into global layout
// so global_load_lds stays linear (m104/m173); ds_read_b128 conflict-free.

__global__ void pack_rowsrc(const float* __restrict__ src, u16* __restrict__ dst,
                            int nShift, int sstride, int rowblk, int total){
  int gid = blockIdx.x*256 + threadIdx.x;
  if (gid >= total) return;
  int g  = gid & 7;
  int n  = (gid >> 3) & ((1<<nShift)-1);
  int kt = gid >> (3+nShift);
  int rowbase = (kt>>2)*rowblk;
  int colbase = (kt&3)*64;
  const float* s = src + (size_t)(rowbase + n)*sstride + colbase + g*8;
  f32x4 a = *(const f32x4*)s;
  f32x4 b = *(const f32x4*)(s+4);
  short8 p;
  p[0]=(short)f2b(a[0]); p[1]=(short)f2b(a[1]); p[2]=(short)f2b(a[2]); p[3]=(short)f2b(a[3]);
  p[4]=(short)f2b(b[0]); p[5]=(short)f2b(b[1]); p[6]=(short)f2b(b[2]); p[7]=(short)f2b(b[3]);
  size_t dbyte = (((size_t)kt<<nShift) + n)*128 + (size_t)((g ^ (n&7))<<4);
  *(short8*)((char*)dst + dbyte) = p;
}

__global__ void pack_colsrc(const float* __restrict__ src, u16* __restrict__ dst,
                            int nShift, int total){
  int gid = blockIdx.x*256 + threadIdx.x;
  if (gid >= total) return;
  int g  = gid & 7;
  int n  = (gid >> 3) & ((1<<nShift)-1);
  int kt = gid >> (3+nShift);
  int N  = 1<<nShift;
  const float* s = src + (size_t)(kt*64 + g*8)*N + n;
  short8 p;
  #pragma unroll
  for (int e=0;e<8;e++) p[e] = (short)f2b(s[(size_t)e*N]);
  size_t dbyte = (((size_t)kt<<nShift) + n)*128 + (size_t)((g ^ (n&7))<<4);
  *(short8*)((char*)dst + dbyte) = p;
}

__global__ void cvt_bf16(const float* __restrict__ src, u16* __restrict__ dst, int n4){
  int i = blockIdx.x*256 + threadIdx.x;
  if (i >= n4) return;
  f32x4 v = *(const f32x4*)(src + (size_t)i*4);
  short4v p;
  p[0]=(short)f2b(v[0]); p[1]=(short)f2b(v[1]); p[2]=(short)f2b(v[2]); p[3]=(short)f2b(v[3]);
  *(short4v*)(dst + (size_t)i*4) = p;
}

// ---------------- old-style GEMM (layer 1 + K-tail tiles) -------------------
// AMODE 0: A chunks = [c0*pe | c1*pe | pe]           (layer 1, KTOT=12 tiles)
// AMODE 1: A chunks = [x (kt 1024..1027) | pe (kt 1028..1031)] tails
template<int BM, int BN, int NT, int NF, int AMODE, int NSPLIT, int KTOT, int KT0>
__launch_bounds__(NT)
__global__ void gemm_meta(const u16* __restrict__ Bt, const u16* __restrict__ peb,
                          const u16* __restrict__ xb, const float* __restrict__ coods,
                          float* __restrict__ part){
  constexpr int WNS  = NF*16;
  constexpr int WN   = BN/WNS;
  constexpr int NWAVE= NT/64;
  constexpr int WM   = NWAVE/WN;
  constexpr int WMS  = BM/WM;
  constexpr int MF   = WMS/16;
  constexpr int CH   = (BN*8)/NT;
  constexpr int PA   = (BM*8)/NT;
  constexpr int KPT  = KTOT/NSPLIT;

  __shared__ __align__(16) u16 As[2][BM*64];
  __shared__ __align__(16) u16 Bs[2][BN*64];

  const int t = threadIdx.x;
  const int w = t>>6, l = t&63;
  const int bid = blockIdx.x;
  const int zz = bid % NSPLIT;
  const int xx = bid / NSPLIT;
  const int r0 = xx*BM;
  const int kt0 = KT0 + zz*KPT;
  const int wm = w/WN, wn = w%WN;
  const int lr = l&15, lk = l>>4;
  const int sg = t&7, srl = t>>3;

  short8 a8[PA];
  u16    axv[PA];
  float  asc[PA];

  auto stage_load = [&](int buf, int kt){
    const char* gb = (const char*)Bt + (size_t)kt*(BN*128);
    #pragma unroll
    for (int p=0;p<CH;p++){
      int cb = p*NT + w*64;
      gll16(gb + (size_t)(cb + l)*16, (char*)Bs[buf] + (size_t)cb*16);
    }
    #pragma unroll
    for (int p=0;p<PA;p++){
      int row = r0 + p*(NT/8) + srl;
      if (AMODE == 0) {
        int sel = kt>>2, i0 = (kt&3)*64;
        asc[p] = sel==0 ? coods[row*2+0] : (sel==1 ? coods[row*2+1] : 1.f);
        a8[p] = *(const short8*)(peb + (size_t)row*256 + i0 + sg*8);
      } else {
        if (kt < 1024) {
          int d = kt>>2, i0 = (kt&3)*64;
          axv[p] = xb[(size_t)row*256 + d];
          a8[p]  = *(const short8*)(peb + (size_t)row*256 + i0 + sg*8);
        } else if (kt < 1028) {
          a8[p]  = *(const short8*)(xb + (size_t)row*256 + (kt-1024)*64 + sg*8);
        } else {
          a8[p]  = *(const short8*)(peb + (size_t)row*256 + (kt-1028)*64 + sg*8);
        }
      }
    }
  };
  auto stage_write = [&](int buf, int kt){
    #pragma unroll
    for (int p=0;p<PA;p++){
      int r = p*(NT/8) + srl;
      short8 out;
      bool raw = (AMODE==0) ? ((kt>>2)==2) : (kt>=1024);
      if (raw) {
        out = a8[p];
      } else {
        float sc = (AMODE==0) ? asc[p] : b2f(axv[p]);
        #pragma unroll
        for (int j=0;j<8;j++) out[j] = (short)f2b(sc * b2f((u16)a8[p][j]));
      }
      *(short8*)((char*)As[buf] + (size_t)r*128 + ((sg ^ (r&7))<<4)) = out;
    }
  };

  f32x4 acc[MF][NF] = {};

  stage_load(0, kt0);
  stage_write(0, kt0);
  __syncthreads();

  for (int kk = 0; kk < KPT; ++kk) {
    const bool pf = (kk+1 < KPT);
    if (pf) stage_load((kk+1)&1, kt0+kk+1);
    const char* Ab = (const char*)As[kk&1];
    const char* Bb = (const char*)Bs[kk&1];
    #pragma unroll
    for (int ki=0; ki<2; ++ki){
      short8 af[MF], bfr[NF];
      const int gq = ki*4 + lk;
      #pragma unroll
      for (int mf=0; mf<MF; ++mf){
        int row = wm*WMS + mf*16 + lr;
        af[mf] = *(const short8*)(Ab + (size_t)row*128 + ((gq ^ (row&7))<<4));
      }
      #pragma unroll
      for (int nf=0; nf<NF; ++nf){
        int n = wn*WNS + nf*16 + lr;
        bfr[nf] = *(const short8*)(Bb + (size_t)n*128 + ((gq ^ (n&7))<<4));
      }
      #pragma unroll
      for (int mf=0; mf<MF; ++mf)
        #pragma unroll
        for (int nf=0; nf<NF; ++nf)
          acc[mf][nf] = __builtin_amdgcn_mfma_f32_16x16x32_bf16(af[mf], bfr[nf], acc[mf][nf], 0,0,0);
    }
    if (pf) stage_write((kk+1)&1, kt0+kk+1);
    __syncthreads();
  }

  #pragma unroll
  for (int mf=0; mf<MF; ++mf){
    #pragma unroll
    for (int nf=0; nf<NF; ++nf){
      int col = wn*WNS + nf*16 + lr;
      #pragma unroll
      for (int rg=0; rg<4; ++rg){
        int row = r0 + wm*WMS + mf*16 + lk*4 + rg;
        atomicAdd(&part[(size_t)row*BN + col], acc[mf][nf][rg]);
      }
    }
  }
}

// ---------------- grouped GEMM (layers 2,3 main part: kt 0..1023) -----------
// Per group d: out += diag(x[:,d]) * (PE . B_d), PE A-fragments in registers
// for the whole kernel. 3-buffer B pipeline, counted vmcnt, 1 barrier/tile.
// CRITICAL: waitcnt+barrier fused in ONE asm (memory clobber) so no ds_read
// can be scheduled between them (plain s_barrier builtin is not a fence).
template<int BM, int BN, int NT, int NF, int NSPLIT>
__launch_bounds__(NT)
__global__ void gemm_grp(const u16* __restrict__ Bt, const u16* __restrict__ peb,
                         const u16* __restrict__ xb, float* __restrict__ part){
  constexpr int WNS=NF*16, WN=BN/WNS, NWAVE=NT/64, WM=NWAVE/WN, WMS=BM/WM, MF=WMS/16;
  constexpr int CH=(BN*8)/NT;
  constexpr int GPB=256/NSPLIT, NTILES=GPB*4;
  constexpr int TILEB=BN*128;              // bytes per staged B tile
  static_assert(BM*GPB == NT*4, "x-stage assumes 4 u16/thread");
  static_assert(CH==2 || CH==4, "vmcnt literals assume CH in {2,4}");

  __shared__ __align__(16) u16 Bs[3*BN*64];
  __shared__ __align__(16) u16 xtile[BM*GPB];

  const int t=threadIdx.x, w=t>>6, l=t&63;
  const int zz=blockIdx.x%NSPLIT, xx=blockIdx.x/NSPLIT;
  const int r0=xx*BM, g0=zz*GPB;
  const int wm=w/WN, wn=w%WN, lr=l&15, lk=l>>4;

  // pe A-fragments, fixed for all groups: af[mf][q] = pe[row, q*32+lk*8 ..+8)
  short8 af[MF][8];
  #pragma unroll
  for (int mf=0; mf<MF; ++mf){
    int row = r0 + wm*WMS + mf*16 + lr;
    #pragma unroll
    for (int q=0;q<8;++q)
      af[mf][q] = *(const short8*)(peb + (size_t)row*256 + q*32 + lk*8);
  }

  auto stageB = [&](int buf, int ti){
    const char* gb = (const char*)Bt + (size_t)(g0*4+ti)*TILEB;
    #pragma unroll
    for (int p=0;p<CH;++p){
      int cb = p*NT + w*64;
      gll16(gb + (size_t)(cb+l)*16, (char*)Bs + (size_t)buf*TILEB + (size_t)cb*16);
    }
  };

  // stage x z-slice (BM rows x GPB groups) into LDS
  {
    int f = t*4;
    int row = f/GPB, dd = f%GPB;
    *(short4v*)&xtile[f] = *(const short4v*)(xb + (size_t)(r0+row)*256 + g0 + dd);
  }
  stageB(0,0); stageB(1,1);
  __syncthreads();     // one-time full drain (pe frags, x writes, first 2 tiles)

  f32x4 acc[MF][NF] = {};
  f32x4 tmp[MF][NF] = {};
  float xs[MF][4];

  for (int g=0; g<GPB; ++g){
    #pragma unroll
    for (int j=0;j<4;++j){
      const int ti = g*4 + j;
      // fused counted-vmcnt + barrier: single asm => nothing schedulable between
      if (g==GPB-1 && j==3)
        asm volatile("s_waitcnt vmcnt(0)\n\ts_barrier" ::: "memory");
      else if constexpr (CH==2)
        asm volatile("s_waitcnt vmcnt(2)\n\ts_barrier" ::: "memory");
      else
        asm volatile("s_waitcnt vmcnt(4)\n\ts_barrier" ::: "memory");
      __builtin_amdgcn_sched_barrier(0);
      if (ti+2 < NTILES) stageB((ti+2)%3, ti+2);     // keep 2 tiles in flight
      if (j==0){
        #pragma unroll
        for (int mf=0; mf<MF; ++mf)
          #pragma unroll
          for (int rg=0; rg<4; ++rg)
            xs[mf][rg] = b2f(xtile[(wm*WMS+mf*16+lk*4+rg)*GPB + g]);
      }
      const char* Bb = (const char*)Bs + (size_t)(ti%3)*TILEB;
      #pragma unroll
      for (int ki=0; ki<2; ++ki){
        const int gq = ki*4+lk, q = j*2+ki;
        short8 bfr[NF];
        #pragma unroll
        for (int nf=0;nf<NF;++nf){
          int n = wn*WNS + nf*16 + lr;
          bfr[nf] = *(const short8*)(Bb + (size_t)n*128 + ((gq^(n&7))<<4));
        }
        #pragma unroll
        for (int mf=0;mf<MF;++mf)
          #pragma unroll
          for (int nf=0;nf<NF;++nf)
            tmp[mf][nf] = __builtin_amdgcn_mfma_f32_16x16x32_bf16(af[mf][q], bfr[nf], tmp[mf][nf],0,0,0);
      }
      if (j==3){
        #pragma unroll
        for (int mf=0;mf<MF;++mf)
          #pragma unroll
          for (int nf=0;nf<NF;++nf){
            #pragma unroll
            for (int rg=0;rg<4;++rg) acc[mf][nf][rg] += xs[mf][rg]*tmp[mf][nf][rg];
            tmp[mf][nf] = (f32x4){0.f,0.f,0.f,0.f};
          }
      }
    }
  }

  #pragma unroll
  for (int mf=0;mf<MF;++mf)
    #pragma unroll
    for (int nf=0;nf<NF;++nf){
      int col = wn*WNS + nf*16 + lr;
      #pragma unroll
      for (int rg=0;rg<4;++rg){
        int row = r0 + wm*WMS + mf*16 + lk*4 + rg;
        atomicAdd(&part[(size_t)row*BN + col], acc[mf][nf][rg]);
      }
    }
}

// ---------------- epilogues -------------------------------------------------
__global__ void reduce_ep1(const float* __restrict__ part, const float* __restrict__ coods,
                           const float* __restrict__ b1w, const float* __restrict__ b1b,
                           const float* __restrict__ alpha, u16* __restrict__ x1b, int total){
  int i = blockIdx.x*256 + threadIdx.x;
  if (i >= total) return;
  int b = i>>8, d = i&255;
  float s = part[i] + coods[b*2]*b1w[d] + coods[b*2+1]*b1w[256+d] + b1b[d];
  float a = alpha[0];
  s = s >= 0.f ? s : a*s;
  x1b[i] = f2b(s);
}

__global__ void reduce_ep2(const float* __restrict__ part, const float* __restrict__ b2b,
                           const float* __restrict__ alpha, u16* __restrict__ x2b, int total){
  int i = blockIdx.x*256 + threadIdx.x;
  if (i >= total) return;
  float s = part[i] + b2b[i&255];
  float a = alpha[0];
  s = s >= 0.f ? s : a*s;
  x2b[i] = f2b(s);
}

__global__ void reduce_ep3(const float* __restrict__ part, const float* __restrict__ b3b,
                           float* __restrict__ out, int total){
  int i = blockIdx.x*256 + threadIdx.x;
  if (i >= total) return;
  out[i] = part[i] + b3b[i&63];
}

// ---------------- host ------------------------------------------------------
extern "C" void kernel_launch(void* const* d_in, const int* in_sizes, int n_in,
                              void* d_out, int out_size, void* d_ws, size_t ws_size,
                              hipStream_t stream){
  const float* coods = (const float*)d_in[0];
  const float* pe    = (const float*)d_in[1];
  const float* W1w   = (const float*)d_in[2];
  const float* b1w   = (const float*)d_in[3];
  const float* W1b   = (const float*)d_in[4];
  const float* b1b   = (const float*)d_in[5];
  const float* W2w   = (const float*)d_in[6];
  const float* b2w   = (const float*)d_in[7];
  const float* W2b   = (const float*)d_in[8];
  const float* b2b   = (const float*)d_in[9];
  const float* W3w   = (const float*)d_in[10];
  const float* b3w   = (const float*)d_in[11];
  const float* W3b   = (const float*)d_in[12];
  const float* b3b   = (const float*)d_in[13];
  const float* alpha = (const float*)d_in[14];
  float* out = (float*)d_out;

  char* ws = (char*)d_ws;
  size_t off = 0;
  auto alloc = [&](size_t bytes)->void*{ void* p = ws + off; off += (bytes + 255) & ~(size_t)255; return p; };
  u16*   B2   = (u16*)  alloc(1032ull*256*128);   // 32.25 MB
  u16*   B3   = (u16*)  alloc(1032ull*64*128);    //  8.06 MB
  u16*   B1   = (u16*)  alloc(12ull*256*128);     //  0.38 MB
  u16*   peb  = (u16*)  alloc(4096ull*256*2);
  u16*   x1b  = (u16*)  alloc(4096ull*256*2);
  u16*   x2b  = (u16*)  alloc(4096ull*256*2);
  float* part = (float*)alloc(4096ull*256*4);     // 4 MB atomic accumulator
  if (ws_size < off) return;

  // --- pack weights ---
  pack_rowsrc<<<2097152/256, 256, 0, stream>>>(W2w, B2, 8, 256, 256, 2097152);
  pack_colsrc<<<8192/256,    256, 0, stream>>>(b2w, B2 + 1024ull*16384, 8, 8192);
  pack_rowsrc<<<8192/256,    256, 0, stream>>>(W2b, B2 + 1028ull*16384, 8, 256, 0, 8192);
  pack_rowsrc<<<524288/256,  256, 0, stream>>>(W3w, B3, 6, 256, 64, 524288);
  pack_colsrc<<<2048/256,    256, 0, stream>>>(b3w, B3 + 1024ull*4096, 6, 2048);
  pack_rowsrc<<<2048/256,    256, 0, stream>>>(W3b, B3 + 1028ull*4096, 6, 256, 0, 2048);
  pack_rowsrc<<<16384/256,   256, 0, stream>>>(W1w, B1, 8, 256, 256, 16384);
  pack_rowsrc<<<8192/256,    256, 0, stream>>>(W1b, B1 + 8ull*16384, 8, 256, 0, 8192);
  cvt_bf16<<<262144/256, 256, 0, stream>>>(pe, peb, 262144);

  // --- layer 1 (old path, K=12 tiles) ---
  hipMemsetAsync(part, 0, 4096ull*256*4, stream);
  gemm_meta<64,256,512,4,0,4,12,0><<<256, 512, 0, stream>>>(B1, peb, nullptr, coods, part);
  reduce_ep1<<<1048576/256, 256, 0, stream>>>(part, coods, b1w, b1b, alpha, x1b, 1048576);

  // --- layer 2: grouped main (kt 0..1023) + tail (kt 1024..1031) ---
  hipMemsetAsync(part, 0, 4096ull*256*4, stream);
  gemm_grp<64,256,512,4,8><<<512, 512, 0, stream>>>(B2, peb, x1b, part);
  gemm_meta<64,256,512,4,1,4,8,1024><<<256, 512, 0, stream>>>(B2, peb, x1b, nullptr, part);
  reduce_ep2<<<1048576/256, 256, 0, stream>>>(part, b2b, alpha, x2b, 1048576);

  // --- layer 3: grouped main + tail ---
  hipMemsetAsync(part, 0, 4096ull*64*4, stream);
  gemm_grp<64,64,256,2,16><<<1024, 256, 0, stream>>>(B3, peb, x2b, part);
  gemm_meta<64,64,256,2,1,4,8,1024><<<256, 256, 0, stream>>>(B3, peb, x2b, nullptr, part);
  reduce_ep3<<<262144/256, 256, 0, stream>>>(part, b3b, out, 262144);
}

// Round 6
// 460.188 us; speedup vs baseline: 1.1056x; 1.1056x over previous
//
#include <hip/hip_runtime.h>
#include <hip/hip_bf16.h>
#include <stdint.h>

// MetaPN: 3-layer per-sample hypernetwork as 3 GEMMs with on-the-fly
// A = x ⊗ pe outer-product structure.  D=256, DT=64, B=4096.
// Round 6: WM=1 grouped GEMM (LDS B-read amplification 1x) with K-split
// across blocks (half for L2, quarter for L3) so the register-resident pe
// panel fits (64/32 VGPR).  4-buffer depth-3 counted-vmcnt pipeline, fused
// waitcnt+barrier asm, transposed conflict-free xtile.

typedef unsigned int u32;
typedef unsigned short u16;
typedef __attribute__((ext_vector_type(8))) short short8;
typedef __attribute__((ext_vector_type(4))) short short4v;
typedef __attribute__((ext_vector_type(4))) float f32x4;

#define DEV static __device__ __forceinline__

DEV float b2f(u16 u){ u32 i = ((u32)u)<<16; float f; __builtin_memcpy(&f,&i,4); return f; }
DEV u16 f2b(float f){ __hip_bfloat16 h = __float2bfloat16(f); u16 u; __builtin_memcpy(&u,&h,2); return u; }

DEV void gll16(const void* g, void* l){
  __builtin_amdgcn_global_load_lds((const __attribute__((address_space(1))) u32*)g,
                                   (__attribute__((address_space(3))) u32*)l, 16, 0, 0);
}

// ---------------- prep: pack weights into bf16 K-tiled swizzled layout -------
// Logical B element (k, n), k = kt*64 + g*8 + e  (g,e in 0..7) stored at byte
// kt*N*128 + n*128 + ((g ^ (n&7))<<4) + e*2.

__global__ void pack_rowsrc(const float* __restrict__ src, u16* __restrict__ dst,
                            int nShift, int sstride, int rowblk, int total){
  int gid = blockIdx.x*256 + threadIdx.x;
  if (gid >= total) return;
  int g  = gid & 7;
  int n  = (gid >> 3) & ((1<<nShift)-1);
  int kt = gid >> (3+nShift);
  int rowbase = (kt>>2)*rowblk;
  int colbase = (kt&3)*64;
  const float* s = src + (size_t)(rowbase + n)*sstride + colbase + g*8;
  f32x4 a = *(const f32x4*)s;
  f32x4 b = *(const f32x4*)(s+4);
  short8 p;
  p[0]=(short)f2b(a[0]); p[1]=(short)f2b(a[1]); p[2]=(short)f2b(a[2]); p[3]=(short)f2b(a[3]);
  p[4]=(short)f2b(b[0]); p[5]=(short)f2b(b[1]); p[6]=(short)f2b(b[2]); p[7]=(short)f2b(b[3]);
  size_t dbyte = (((size_t)kt<<nShift) + n)*128 + (size_t)((g ^ (n&7))<<4);
  *(short8*)((char*)dst + dbyte) = p;
}

__global__ void pack_colsrc(const float* __restrict__ src, u16* __restrict__ dst,
                            int nShift, int total){
  int gid = blockIdx.x*256 + threadIdx.x;
  if (gid >= total) return;
  int g  = gid & 7;
  int n  = (gid >> 3) & ((1<<nShift)-1);
  int kt = gid >> (3+nShift);
  int N  = 1<<nShift;
  const float* s = src + (size_t)(kt*64 + g*8)*N + n;
  short8 p;
  #pragma unroll
  for (int e=0;e<8;e++) p[e] = (short)f2b(s[(size_t)e*N]);
  size_t dbyte = (((size_t)kt<<nShift) + n)*128 + (size_t)((g ^ (n&7))<<4);
  *(short8*)((char*)dst + dbyte) = p;
}

__global__ void cvt_bf16(const float* __restrict__ src, u16* __restrict__ dst, int n4){
  int i = blockIdx.x*256 + threadIdx.x;
  if (i >= n4) return;
  f32x4 v = *(const f32x4*)(src + (size_t)i*4);
  short4v p;
  p[0]=(short)f2b(v[0]); p[1]=(short)f2b(v[1]); p[2]=(short)f2b(v[2]); p[3]=(short)f2b(v[3]);
  *(short4v*)(dst + (size_t)i*4) = p;
}

// ---------------- old-style GEMM (layer 1 + K-tail tiles) -------------------
template<int BM, int BN, int NT, int NF, int AMODE, int NSPLIT, int KTOT, int KT0>
__launch_bounds__(NT)
__global__ void gemm_meta(const u16* __restrict__ Bt, const u16* __restrict__ peb,
                          const u16* __restrict__ xb, const float* __restrict__ coods,
                          float* __restrict__ part){
  constexpr int WNS  = NF*16;
  constexpr int WN   = BN/WNS;
  constexpr int NWAVE= NT/64;
  constexpr int WM   = NWAVE/WN;
  constexpr int WMS  = BM/WM;
  constexpr int MF   = WMS/16;
  constexpr int CH   = (BN*8)/NT;
  constexpr int PA   = (BM*8)/NT;
  constexpr int KPT  = KTOT/NSPLIT;

  __shared__ __align__(16) u16 As[2][BM*64];
  __shared__ __align__(16) u16 Bs[2][BN*64];

  const int t = threadIdx.x;
  const int w = t>>6, l = t&63;
  const int bid = blockIdx.x;
  const int zz = bid % NSPLIT;
  const int xx = bid / NSPLIT;
  const int r0 = xx*BM;
  const int kt0 = KT0 + zz*KPT;
  const int wm = w/WN, wn = w%WN;
  const int lr = l&15, lk = l>>4;
  const int sg = t&7, srl = t>>3;

  short8 a8[PA];
  u16    axv[PA];
  float  asc[PA];

  auto stage_load = [&](int buf, int kt){
    const char* gb = (const char*)Bt + (size_t)kt*(BN*128);
    #pragma unroll
    for (int p=0;p<CH;p++){
      int cb = p*NT + w*64;
      gll16(gb + (size_t)(cb + l)*16, (char*)Bs[buf] + (size_t)cb*16);
    }
    #pragma unroll
    for (int p=0;p<PA;p++){
      int row = r0 + p*(NT/8) + srl;
      if (AMODE == 0) {
        int sel = kt>>2, i0 = (kt&3)*64;
        asc[p] = sel==0 ? coods[row*2+0] : (sel==1 ? coods[row*2+1] : 1.f);
        a8[p] = *(const short8*)(peb + (size_t)row*256 + i0 + sg*8);
      } else {
        if (kt < 1024) {
          int d = kt>>2, i0 = (kt&3)*64;
          axv[p] = xb[(size_t)row*256 + d];
          a8[p]  = *(const short8*)(peb + (size_t)row*256 + i0 + sg*8);
        } else if (kt < 1028) {
          a8[p]  = *(const short8*)(xb + (size_t)row*256 + (kt-1024)*64 + sg*8);
        } else {
          a8[p]  = *(const short8*)(peb + (size_t)row*256 + (kt-1028)*64 + sg*8);
        }
      }
    }
  };
  auto stage_write = [&](int buf, int kt){
    #pragma unroll
    for (int p=0;p<PA;p++){
      int r = p*(NT/8) + srl;
      short8 out;
      bool raw = (AMODE==0) ? ((kt>>2)==2) : (kt>=1024);
      if (raw) {
        out = a8[p];
      } else {
        float sc = (AMODE==0) ? asc[p] : b2f(axv[p]);
        #pragma unroll
        for (int j=0;j<8;j++) out[j] = (short)f2b(sc * b2f((u16)a8[p][j]));
      }
      *(short8*)((char*)As[buf] + (size_t)r*128 + ((sg ^ (r&7))<<4)) = out;
    }
  };

  f32x4 acc[MF][NF] = {};

  stage_load(0, kt0);
  stage_write(0, kt0);
  __syncthreads();

  for (int kk = 0; kk < KPT; ++kk) {
    const bool pf = (kk+1 < KPT);
    if (pf) stage_load((kk+1)&1, kt0+kk+1);
    const char* Ab = (const char*)As[kk&1];
    const char* Bb = (const char*)Bs[kk&1];
    #pragma unroll
    for (int ki=0; ki<2; ++ki){
      short8 af[MF], bfr[NF];
      const int gq = ki*4 + lk;
      #pragma unroll
      for (int mf=0; mf<MF; ++mf){
        int row = wm*WMS + mf*16 + lr;
        af[mf] = *(const short8*)(Ab + (size_t)row*128 + ((gq ^ (row&7))<<4));
      }
      #pragma unroll
      for (int nf=0; nf<NF; ++nf){
        int n = wn*WNS + nf*16 + lr;
        bfr[nf] = *(const short8*)(Bb + (size_t)n*128 + ((gq ^ (n&7))<<4));
      }
      #pragma unroll
      for (int mf=0; mf<MF; ++mf)
        #pragma unroll
        for (int nf=0; nf<NF; ++nf)
          acc[mf][nf] = __builtin_amdgcn_mfma_f32_16x16x32_bf16(af[mf], bfr[nf], acc[mf][nf], 0,0,0);
    }
    if (pf) stage_write((kk+1)&1, kt0+kk+1);
    __syncthreads();
  }

  #pragma unroll
  for (int mf=0; mf<MF; ++mf){
    #pragma unroll
    for (int nf=0; nf<NF; ++nf){
      int col = wn*WNS + nf*16 + lr;
      #pragma unroll
      for (int rg=0; rg<4; ++rg){
        int row = r0 + wm*WMS + mf*16 + lk*4 + rg;
        atomicAdd(&part[(size_t)row*BN + col], acc[mf][nf][rg]);
      }
    }
  }
}

// ---------------- grouped GEMM v2 (layers 2,3 main: kt 0..1023) -------------
// WM=1: every wave owns all BM rows, distinct cols -> each B byte read from
// LDS exactly once.  K split across blocks (KSPLIT): pe panel = 256/KSPLIT
// wide -> af regs = BM*2/KSPLIT.  Per group d (this block's k-slice):
//   tmp = PE_slice . B_d_slice ; acc += diag(x[:,d]) * tmp
// x-scaling distributes over K-splits since `part` accumulates atomically.
template<int BM, int BN, int NT, int NF, int NSG, int KSPLIT>
__launch_bounds__(NT, 2)
__global__ void gemm_grp2(const u16* __restrict__ Bt, const u16* __restrict__ peb,
                          const u16* __restrict__ xb, float* __restrict__ part){
  constexpr int WNS = NF*16;
  constexpr int WN  = BN/WNS;
  static_assert(NT/64 == WN, "WM must be 1");
  constexpr int MF  = BM/16;
  constexpr int CH  = (BN*8)/NT;       // 16B chunks per thread per stage
  constexpr int TPG = 4/KSPLIT;        // tiles per group in this block
  constexpr int AFQ = TPG*2;           // q-slices (32 k each) per block
  constexpr int GPB = 256/NSG;         // groups per block
  constexpr int NPH = GPB*TPG;         // phases (tiles) per block
  constexpr int ZC  = NSG*KSPLIT;
  constexpr int TILEB = BN*128;
  constexpr int TPW = NT/GPB;          // threads per group for xtile stage
  constexpr int XE  = BM/TPW;          // rows per thread for xtile stage
  static_assert(NPH >= 4, "pipeline depth");

  __shared__ __align__(16) u16 Bs[4*BN*64];
  __shared__ __align__(16) u16 xtile[GPB*BM];   // [g][row] (transposed)

  const int t=threadIdx.x, w=t>>6, l=t&63;
  const int zz = blockIdx.x % ZC, xx = blockIdx.x / ZC;
  const int gsl = zz / KSPLIT, kz = zz % KSPLIT;
  const int r0 = xx*BM, g0 = gsl*GPB;
  const int wn = w;                     // WM=1
  const int lr = l&15, lk = l>>4;

  auto stageB = [&](int buf, int ph){
    int g = ph / TPG, jj = ph % TPG;
    int kt = (g0+g)*4 + kz*TPG + jj;
    const char* gb = (const char*)Bt + (size_t)kt*TILEB;
    #pragma unroll
    for (int p=0;p<CH;++p){
      int cb = p*NT + w*64;
      gll16(gb + (size_t)(cb+l)*16, (char*)Bs + (size_t)buf*TILEB + (size_t)cb*16);
    }
  };

  // prologue: first 3 B tiles + x slab + pe fragments
  stageB(0,0); stageB(1,1); stageB(2,2);
  {
    int g = t / TPW, row0 = (t % TPW) * XE;
    #pragma unroll
    for (int e=0;e<XE;++e)
      xtile[g*BM + row0 + e] = xb[(size_t)(r0+row0+e)*256 + g0 + g];
  }
  short8 af[MF][AFQ];
  #pragma unroll
  for (int mf=0; mf<MF; ++mf){
    int row = r0 + mf*16 + lr;
    #pragma unroll
    for (int q=0;q<AFQ;++q)
      af[mf][q] = *(const short8*)(peb + (size_t)row*256 + kz*(TPG*64) + q*32 + lk*8);
  }
  __syncthreads();   // one-time full drain

  f32x4 acc[MF][NF] = {};
  f32x4 tmp[MF][NF] = {};

  auto scale_group = [&](int gg){
    #pragma unroll
    for (int mf=0;mf<MF;++mf){
      #pragma unroll
      for (int rg=0;rg<4;++rg){
        float xv = b2f(xtile[gg*BM + mf*16 + lk*4 + rg]);
        #pragma unroll
        for (int nf=0;nf<NF;++nf){
          acc[mf][nf][rg] += xv * tmp[mf][nf][rg];
          tmp[mf][nf][rg] = 0.f;
        }
      }
    }
  };

  for (int g=0; g<GPB; ++g){
    #pragma unroll
    for (int jj=0; jj<TPG; ++jj){
      const int ti = g*TPG + jj;
      const int rem = (NPH-1) - ti;
      __builtin_amdgcn_sched_barrier(0);
      if (rem >= 2) {
        if constexpr (CH==4) asm volatile("s_waitcnt vmcnt(8)\n\ts_barrier" ::: "memory");
        else                 asm volatile("s_waitcnt vmcnt(4)\n\ts_barrier" ::: "memory");
      } else if (rem == 1) {
        if constexpr (CH==4) asm volatile("s_waitcnt vmcnt(4)\n\ts_barrier" ::: "memory");
        else                 asm volatile("s_waitcnt vmcnt(2)\n\ts_barrier" ::: "memory");
      } else {
        asm volatile("s_waitcnt vmcnt(0)\n\ts_barrier" ::: "memory");
      }
      __builtin_amdgcn_sched_barrier(0);
      if (ti+3 < NPH) stageB((ti+3)&3, ti+3);
      if (jj==0 && g>0) scale_group(g-1);     // overlap VALU with ds_read latency
      const char* Bb = (const char*)Bs + (size_t)(ti&3)*TILEB;
      #pragma unroll
      for (int ki=0; ki<2; ++ki){
        const int gq = ki*4 + lk;
        const int q  = jj*2 + ki;
        short8 bfr[NF];
        #pragma unroll
        for (int nf=0;nf<NF;++nf){
          int n = wn*WNS + nf*16 + lr;
          bfr[nf] = *(const short8*)(Bb + (size_t)n*128 + ((gq^(n&7))<<4));
        }
        #pragma unroll
        for (int mf=0;mf<MF;++mf)
          #pragma unroll
          for (int nf=0;nf<NF;++nf)
            tmp[mf][nf] = __builtin_amdgcn_mfma_f32_16x16x32_bf16(af[mf][q], bfr[nf], tmp[mf][nf],0,0,0);
      }
    }
  }
  scale_group(GPB-1);

  #pragma unroll
  for (int mf=0;mf<MF;++mf)
    #pragma unroll
    for (int nf=0;nf<NF;++nf){
      int col = wn*WNS + nf*16 + lr;
      #pragma unroll
      for (int rg=0;rg<4;++rg){
        int row = r0 + mf*16 + lk*4 + rg;
        atomicAdd(&part[(size_t)row*BN + col], acc[mf][nf][rg]);
      }
    }
}

// ---------------- epilogues -------------------------------------------------
__global__ void reduce_ep1(const float* __restrict__ part, const float* __restrict__ coods,
                           const float* __restrict__ b1w, const float* __restrict__ b1b,
                           const float* __restrict__ alpha, u16* __restrict__ x1b, int total){
  int i = blockIdx.x*256 + threadIdx.x;
  if (i >= total) return;
  int b = i>>8, d = i&255;
  float s = part[i] + coods[b*2]*b1w[d] + coods[b*2+1]*b1w[256+d] + b1b[d];
  float a = alpha[0];
  s = s >= 0.f ? s : a*s;
  x1b[i] = f2b(s);
}

__global__ void reduce_ep2(const float* __restrict__ part, const float* __restrict__ b2b,
                           const float* __restrict__ alpha, u16* __restrict__ x2b, int total){
  int i = blockIdx.x*256 + threadIdx.x;
  if (i >= total) return;
  float s = part[i] + b2b[i&255];
  float a = alpha[0];
  s = s >= 0.f ? s : a*s;
  x2b[i] = f2b(s);
}

__global__ void reduce_ep3(const float* __restrict__ part, const float* __restrict__ b3b,
                           float* __restrict__ out, int total){
  int i = blockIdx.x*256 + threadIdx.x;
  if (i >= total) return;
  out[i] = part[i] + b3b[i&63];
}

// ---------------- host ------------------------------------------------------
extern "C" void kernel_launch(void* const* d_in, const int* in_sizes, int n_in,
                              void* d_out, int out_size, void* d_ws, size_t ws_size,
                              hipStream_t stream){
  const float* coods = (const float*)d_in[0];
  const float* pe    = (const float*)d_in[1];
  const float* W1w   = (const float*)d_in[2];
  const float* b1w   = (const float*)d_in[3];
  const float* W1b   = (const float*)d_in[4];
  const float* b1b   = (const float*)d_in[5];
  const float* W2w   = (const float*)d_in[6];
  const float* b2w   = (const float*)d_in[7];
  const float* W2b   = (const float*)d_in[8];
  const float* b2b   = (const float*)d_in[9];
  const float* W3w   = (const float*)d_in[10];
  const float* b3w   = (const float*)d_in[11];
  const float* W3b   = (const float*)d_in[12];
  const float* b3b   = (const float*)d_in[13];
  const float* alpha = (const float*)d_in[14];
  float* out = (float*)d_out;

  char* ws = (char*)d_ws;
  size_t off = 0;
  auto alloc = [&](size_t bytes)->void*{ void* p = ws + off; off += (bytes + 255) & ~(size_t)255; return p; };
  u16*   B2   = (u16*)  alloc(1032ull*256*128);   // 32.25 MB
  u16*   B3   = (u16*)  alloc(1032ull*64*128);    //  8.06 MB
  u16*   B1   = (u16*)  alloc(12ull*256*128);     //  0.38 MB
  u16*   peb  = (u16*)  alloc(4096ull*256*2);
  u16*   x1b  = (u16*)  alloc(4096ull*256*2);
  u16*   x2b  = (u16*)  alloc(4096ull*256*2);
  float* part = (float*)alloc(4096ull*256*4);     // 4 MB atomic accumulator
  if (ws_size < off) return;

  // --- pack weights ---
  pack_rowsrc<<<2097152/256, 256, 0, stream>>>(W2w, B2, 8, 256, 256, 2097152);
  pack_colsrc<<<8192/256,    256, 0, stream>>>(b2w, B2 + 1024ull*16384, 8, 8192);
  pack_rowsrc<<<8192/256,    256, 0, stream>>>(W2b, B2 + 1028ull*16384, 8, 256, 0, 8192);
  pack_rowsrc<<<524288/256,  256, 0, stream>>>(W3w, B3, 6, 256, 64, 524288);
  pack_colsrc<<<2048/256,    256, 0, stream>>>(b3w, B3 + 1024ull*4096, 6, 2048);
  pack_rowsrc<<<2048/256,    256, 0, stream>>>(W3b, B3 + 1028ull*4096, 6, 256, 0, 2048);
  pack_rowsrc<<<16384/256,   256, 0, stream>>>(W1w, B1, 8, 256, 256, 16384);
  pack_rowsrc<<<8192/256,    256, 0, stream>>>(W1b, B1 + 8ull*16384, 8, 256, 0, 8192);
  cvt_bf16<<<262144/256, 256, 0, stream>>>(pe, peb, 262144);

  // --- layer 1 (old path, K=12 tiles) ---
  hipMemsetAsync(part, 0, 4096ull*256*4, stream);
  gemm_meta<64,256,512,4,0,4,12,0><<<256, 512, 0, stream>>>(B1, peb, nullptr, coods, part);
  reduce_ep1<<<1048576/256, 256, 0, stream>>>(part, coods, b1w, b1b, alpha, x1b, 1048576);

  // --- layer 2: grouped v2 (k-half split, z=8 -> XCD-resident 4MB B slices) ---
  hipMemsetAsync(part, 0, 4096ull*256*4, stream);
  gemm_grp2<64,256,512,2,4,2><<<512, 512, 0, stream>>>(B2, peb, x1b, part);
  gemm_meta<64,256,512,4,1,4,8,1024><<<256, 512, 0, stream>>>(B2, peb, x1b, nullptr, part);
  reduce_ep2<<<1048576/256, 256, 0, stream>>>(part, b2b, alpha, x2b, 1048576);

  // --- layer 3: grouped v2 (k-quarter split, 40KB LDS -> 4 blocks/CU) ---
  hipMemsetAsync(part, 0, 4096ull*64*4, stream);
  gemm_grp2<64,64,256,1,4,4><<<1024, 256, 0, stream>>>(B3, peb, x2b, part);
  gemm_meta<64,64,256,2,1,4,8,1024><<<256, 256, 0, stream>>>(B3, peb, x2b, nullptr, part);
  reduce_ep3<<<262144/256, 256, 0, stream>>>(part, b3b, out, 262144);
}

// Round 7
// 384.976 us; speedup vs baseline: 1.3216x; 1.1954x over previous
//
#include <hip/hip_runtime.h>
#include <hip/hip_bf16.h>
#include <stdint.h>

// MetaPN: 3-layer per-sample hypernetwork as 3 GEMMs with on-the-fly
// A = x ⊗ pe outer-product structure.  D=256, DT=64, B=4096.
// Round 7: grouped GEMM v3 — register-A (pe panel in VGPRs, deferred x-scale),
// WM=1, 2 superbuffers, ONE fused {vmcnt(0) lgkmcnt(0); s_barrier} per
// superphase with stage-after-barrier (T3 minimum), tiled for 2-4 blocks/CU.

typedef unsigned int u32;
typedef unsigned short u16;
typedef __attribute__((ext_vector_type(8))) short short8;
typedef __attribute__((ext_vector_type(4))) short short4v;
typedef __attribute__((ext_vector_type(4))) float f32x4;

#define DEV static __device__ __forceinline__

DEV float b2f(u16 u){ u32 i = ((u32)u)<<16; float f; __builtin_memcpy(&f,&i,4); return f; }
DEV u16 f2b(float f){ __hip_bfloat16 h = __float2bfloat16(f); u16 u; __builtin_memcpy(&u,&h,2); return u; }

DEV void gll16(const void* g, void* l){
  __builtin_amdgcn_global_load_lds((const __attribute__((address_space(1))) u32*)g,
                                   (__attribute__((address_space(3))) u32*)l, 16, 0, 0);
}

// ---------------- prep: pack weights into bf16 K-tiled swizzled layout -------
// Logical B element (k, n), k = kt*64 + g*8 + e  (g,e in 0..7) stored at byte
// kt*N*128 + n*128 + ((g ^ (n&7))<<4) + e*2.

__global__ void pack_rowsrc(const float* __restrict__ src, u16* __restrict__ dst,
                            int nShift, int sstride, int rowblk, int total){
  int gid = blockIdx.x*256 + threadIdx.x;
  if (gid >= total) return;
  int g  = gid & 7;
  int n  = (gid >> 3) & ((1<<nShift)-1);
  int kt = gid >> (3+nShift);
  int rowbase = (kt>>2)*rowblk;
  int colbase = (kt&3)*64;
  const float* s = src + (size_t)(rowbase + n)*sstride + colbase + g*8;
  f32x4 a = *(const f32x4*)s;
  f32x4 b = *(const f32x4*)(s+4);
  short8 p;
  p[0]=(short)f2b(a[0]); p[1]=(short)f2b(a[1]); p[2]=(short)f2b(a[2]); p[3]=(short)f2b(a[3]);
  p[4]=(short)f2b(b[0]); p[5]=(short)f2b(b[1]); p[6]=(short)f2b(b[2]); p[7]=(short)f2b(b[3]);
  size_t dbyte = (((size_t)kt<<nShift) + n)*128 + (size_t)((g ^ (n&7))<<4);
  *(short8*)((char*)dst + dbyte) = p;
}

__global__ void pack_colsrc(const float* __restrict__ src, u16* __restrict__ dst,
                            int nShift, int total){
  int gid = blockIdx.x*256 + threadIdx.x;
  if (gid >= total) return;
  int g  = gid & 7;
  int n  = (gid >> 3) & ((1<<nShift)-1);
  int kt = gid >> (3+nShift);
  int N  = 1<<nShift;
  const float* s = src + (size_t)(kt*64 + g*8)*N + n;
  short8 p;
  #pragma unroll
  for (int e=0;e<8;e++) p[e] = (short)f2b(s[(size_t)e*N]);
  size_t dbyte = (((size_t)kt<<nShift) + n)*128 + (size_t)((g ^ (n&7))<<4);
  *(short8*)((char*)dst + dbyte) = p;
}

__global__ void cvt_bf16(const float* __restrict__ src, u16* __restrict__ dst, int n4){
  int i = blockIdx.x*256 + threadIdx.x;
  if (i >= n4) return;
  f32x4 v = *(const f32x4*)(src + (size_t)i*4);
  short4v p;
  p[0]=(short)f2b(v[0]); p[1]=(short)f2b(v[1]); p[2]=(short)f2b(v[2]); p[3]=(short)f2b(v[3]);
  *(short4v*)(dst + (size_t)i*4) = p;
}

// ---------------- old-style GEMM (layer 1 + K-tail tiles) -------------------
template<int BM, int BN, int NT, int NF, int AMODE, int NSPLIT, int KTOT, int KT0>
__launch_bounds__(NT)
__global__ void gemm_meta(const u16* __restrict__ Bt, const u16* __restrict__ peb,
                          const u16* __restrict__ xb, const float* __restrict__ coods,
                          float* __restrict__ part){
  constexpr int WNS  = NF*16;
  constexpr int WN   = BN/WNS;
  constexpr int NWAVE= NT/64;
  constexpr int WM   = NWAVE/WN;
  constexpr int WMS  = BM/WM;
  constexpr int MF   = WMS/16;
  constexpr int CH   = (BN*8)/NT;
  constexpr int PA   = (BM*8)/NT;
  constexpr int KPT  = KTOT/NSPLIT;

  __shared__ __align__(16) u16 As[2][BM*64];
  __shared__ __align__(16) u16 Bs[2][BN*64];

  const int t = threadIdx.x;
  const int w = t>>6, l = t&63;
  const int bid = blockIdx.x;
  const int zz = bid % NSPLIT;
  const int xx = bid / NSPLIT;
  const int r0 = xx*BM;
  const int kt0 = KT0 + zz*KPT;
  const int wm = w/WN, wn = w%WN;
  const int lr = l&15, lk = l>>4;
  const int sg = t&7, srl = t>>3;

  short8 a8[PA];
  u16    axv[PA];
  float  asc[PA];

  auto stage_load = [&](int buf, int kt){
    const char* gb = (const char*)Bt + (size_t)kt*(BN*128);
    #pragma unroll
    for (int p=0;p<CH;p++){
      int cb = p*NT + w*64;
      gll16(gb + (size_t)(cb + l)*16, (char*)Bs[buf] + (size_t)cb*16);
    }
    #pragma unroll
    for (int p=0;p<PA;p++){
      int row = r0 + p*(NT/8) + srl;
      if (AMODE == 0) {
        int sel = kt>>2, i0 = (kt&3)*64;
        asc[p] = sel==0 ? coods[row*2+0] : (sel==1 ? coods[row*2+1] : 1.f);
        a8[p] = *(const short8*)(peb + (size_t)row*256 + i0 + sg*8);
      } else {
        if (kt < 1024) {
          int d = kt>>2, i0 = (kt&3)*64;
          axv[p] = xb[(size_t)row*256 + d];
          a8[p]  = *(const short8*)(peb + (size_t)row*256 + i0 + sg*8);
        } else if (kt < 1028) {
          a8[p]  = *(const short8*)(xb + (size_t)row*256 + (kt-1024)*64 + sg*8);
        } else {
          a8[p]  = *(const short8*)(peb + (size_t)row*256 + (kt-1028)*64 + sg*8);
        }
      }
    }
  };
  auto stage_write = [&](int buf, int kt){
    #pragma unroll
    for (int p=0;p<PA;p++){
      int r = p*(NT/8) + srl;
      short8 out;
      bool raw = (AMODE==0) ? ((kt>>2)==2) : (kt>=1024);
      if (raw) {
        out = a8[p];
      } else {
        float sc = (AMODE==0) ? asc[p] : b2f(axv[p]);
        #pragma unroll
        for (int j=0;j<8;j++) out[j] = (short)f2b(sc * b2f((u16)a8[p][j]));
      }
      *(short8*)((char*)As[buf] + (size_t)r*128 + ((sg ^ (r&7))<<4)) = out;
    }
  };

  f32x4 acc[MF][NF] = {};

  stage_load(0, kt0);
  stage_write(0, kt0);
  __syncthreads();

  for (int kk = 0; kk < KPT; ++kk) {
    const bool pf = (kk+1 < KPT);
    if (pf) stage_load((kk+1)&1, kt0+kk+1);
    const char* Ab = (const char*)As[kk&1];
    const char* Bb = (const char*)Bs[kk&1];
    #pragma unroll
    for (int ki=0; ki<2; ++ki){
      short8 af[MF], bfr[NF];
      const int gq = ki*4 + lk;
      #pragma unroll
      for (int mf=0; mf<MF; ++mf){
        int row = wm*WMS + mf*16 + lr;
        af[mf] = *(const short8*)(Ab + (size_t)row*128 + ((gq ^ (row&7))<<4));
      }
      #pragma unroll
      for (int nf=0; nf<NF; ++nf){
        int n = wn*WNS + nf*16 + lr;
        bfr[nf] = *(const short8*)(Bb + (size_t)n*128 + ((gq ^ (n&7))<<4));
      }
      #pragma unroll
      for (int mf=0; mf<MF; ++mf)
        #pragma unroll
        for (int nf=0; nf<NF; ++nf)
          acc[mf][nf] = __builtin_amdgcn_mfma_f32_16x16x32_bf16(af[mf], bfr[nf], acc[mf][nf], 0,0,0);
    }
    if (pf) stage_write((kk+1)&1, kt0+kk+1);
    __syncthreads();
  }

  #pragma unroll
  for (int mf=0; mf<MF; ++mf){
    #pragma unroll
    for (int nf=0; nf<NF; ++nf){
      int col = wn*WNS + nf*16 + lr;
      #pragma unroll
      for (int rg=0; rg<4; ++rg){
        int row = r0 + wm*WMS + mf*16 + lk*4 + rg;
        atomicAdd(&part[(size_t)row*BN + col], acc[mf][nf][rg]);
      }
    }
  }
}

// ---------------- grouped GEMM v3 (layers 2,3 main: kt 0..1023) -------------
// WM=1; pe panel in registers (af), deferred x-scale per group.  Superphase =
// one d-group's k-slice (TPG tiles).  2 superbuffers; loop body:
//   fused {s_waitcnt vmcnt(0) lgkmcnt(0); s_barrier}  -> stage(sp+1) ->
//   scale(sp-1) -> ds_read+MFMA(sp).
// Stage-after-barrier: buffer cur^1 was last read in sp-1, and every wave
// passed the barrier after consuming it -> DMA write is safe.  vmcnt(0) at
// head only waits stage(sp) (issued a full superphase earlier).
template<int BM, int BN, int NGLOB, int NT, int NF, int NSG, int KSPLIT>
__launch_bounds__(NT, 2)
__global__ void gemm_grp3(const u16* __restrict__ Bt, const u16* __restrict__ peb,
                          const u16* __restrict__ xb, float* __restrict__ part){
  constexpr int WNS = NF*16;
  constexpr int WN  = BN/WNS;
  static_assert(NT/64 == WN, "WM must be 1");
  constexpr int MF  = BM/16;
  constexpr int TPG = 4/KSPLIT;          // tiles per group in this block
  constexpr int AFQ = TPG*2;             // 32k q-slices held in registers
  constexpr int GPB = 256/NSG;           // groups per block
  constexpr int NSP = GPB;               // superphases (1 per group)
  constexpr int ZC  = NSG*KSPLIT;
  constexpr int NYY = NGLOB/BN;
  constexpr int TILE = BN*128;           // bytes per staged tile slice
  constexpr int SUPB = TPG*TILE;         // superbuffer bytes
  constexpr int CH  = (BN*8)/NT;         // gll chunks per thread per tile
  constexpr int XE  = (GPB*BM)/NT;       // xtile elems per thread

  __shared__ __align__(16) u16 Bs[2*SUPB/2];     // 2 superbuffers (u16 count)
  __shared__ __align__(16) u16 xtile[GPB*BM];    // [g][row]

  const int t=threadIdx.x, w=t>>6, l=t&63;
  const int bid = blockIdx.x;
  const int c  = bid % (ZC*NYY);        // fastest-varying => pinned per XCD
  const int zz = c % ZC, yy = c / ZC;
  const int xx = bid / (ZC*NYY);
  const int gsl = zz / KSPLIT, kz = zz % KSPLIT;
  const int r0 = xx*BM, g0 = gsl*GPB, c0 = yy*BN;
  const int wn = w;                      // WM=1
  const int lr = l&15, lk = l>>4;

  auto stageB = [&](int buf, int sp){
    #pragma unroll
    for (int jj=0;jj<TPG;++jj){
      int kt = (g0+sp)*4 + kz*TPG + jj;
      const char* gb = (const char*)Bt + (size_t)kt*(NGLOB*128) + (size_t)c0*128;
      #pragma unroll
      for (int p=0;p<CH;++p){
        int cb = p*NT + w*64;
        gll16(gb + (size_t)(cb+l)*16,
              (char*)Bs + (size_t)buf*SUPB + (size_t)jj*TILE + (size_t)cb*16);
      }
    }
  };

  // prologue: first superbuffer DMA, then x slab + pe fragments
  stageB(0, 0);
  #pragma unroll
  for (int e=0;e<XE;++e){
    int f = t*XE + e;
    int g = f/BM, row = f%BM;
    xtile[f] = xb[(size_t)(r0+row)*256 + g0 + g];
  }
  short8 af[MF][AFQ];
  #pragma unroll
  for (int mf=0; mf<MF; ++mf){
    int row = r0 + mf*16 + lr;
    #pragma unroll
    for (int q=0;q<AFQ;++q)
      af[mf][q] = *(const short8*)(peb + (size_t)row*256 + kz*(TPG*64) + q*32 + lk*8);
  }

  f32x4 acc[MF][NF] = {};
  f32x4 tmp[MF][NF] = {};

  auto scale_group = [&](int gg){
    #pragma unroll
    for (int mf=0;mf<MF;++mf){
      #pragma unroll
      for (int rg=0;rg<4;++rg){
        float xv = b2f(xtile[gg*BM + mf*16 + lk*4 + rg]);
        #pragma unroll
        for (int nf=0;nf<NF;++nf){
          acc[mf][nf][rg] += xv * tmp[mf][nf][rg];
          tmp[mf][nf][rg] = 0.f;
        }
      }
    }
  };

  int cur = 0;
  for (int sp=0; sp<NSP; ++sp){
    // fused full-wait + barrier: stage(sp) landed in buffer cur; xtile visible
    asm volatile("s_waitcnt vmcnt(0) lgkmcnt(0)\n\ts_barrier" ::: "memory");
    __builtin_amdgcn_sched_barrier(0);
    if (sp+1 < NSP) stageB(cur^1, sp+1);      // buffer cur^1 free (read in sp-1)
    if (sp > 0) scale_group(sp-1);            // overlap VALU with ds_read latency
    const char* Sb = (const char*)Bs + (size_t)cur*SUPB;
    __builtin_amdgcn_s_setprio(1);
    #pragma unroll
    for (int jj=0;jj<TPG;++jj){
      const char* Bb = Sb + (size_t)jj*TILE;
      #pragma unroll
      for (int ki=0; ki<2; ++ki){
        const int gq = ki*4 + lk;
        const int q  = jj*2 + ki;
        short8 bfr[NF];
        #pragma unroll
        for (int nf=0;nf<NF;++nf){
          int n = wn*WNS + nf*16 + lr;
          bfr[nf] = *(const short8*)(Bb + (size_t)n*128 + ((gq^(n&7))<<4));
        }
        #pragma unroll
        for (int mf=0;mf<MF;++mf)
          #pragma unroll
          for (int nf=0;nf<NF;++nf)
            tmp[mf][nf] = __builtin_amdgcn_mfma_f32_16x16x32_bf16(af[mf][q], bfr[nf], tmp[mf][nf],0,0,0);
      }
    }
    __builtin_amdgcn_s_setprio(0);
    cur ^= 1;
  }
  scale_group(NSP-1);

  #pragma unroll
  for (int mf=0;mf<MF;++mf)
    #pragma unroll
    for (int nf=0;nf<NF;++nf){
      int col = c0 + wn*WNS + nf*16 + lr;
      #pragma unroll
      for (int rg=0;rg<4;++rg){
        int row = r0 + mf*16 + lk*4 + rg;
        atomicAdd(&part[(size_t)row*NGLOB + col], acc[mf][nf][rg]);
      }
    }
}

// ---------------- epilogues -------------------------------------------------
__global__ void reduce_ep1(const float* __restrict__ part, const float* __restrict__ coods,
                           const float* __restrict__ b1w, const float* __restrict__ b1b,
                           const float* __restrict__ alpha, u16* __restrict__ x1b, int total){
  int i = blockIdx.x*256 + threadIdx.x;
  if (i >= total) return;
  int b = i>>8, d = i&255;
  float s = part[i] + coods[b*2]*b1w[d] + coods[b*2+1]*b1w[256+d] + b1b[d];
  float a = alpha[0];
  s = s >= 0.f ? s : a*s;
  x1b[i] = f2b(s);
}

__global__ void reduce_ep2(const float* __restrict__ part, const float* __restrict__ b2b,
                           const float* __restrict__ alpha, u16* __restrict__ x2b, int total){
  int i = blockIdx.x*256 + threadIdx.x;
  if (i >= total) return;
  float s = part[i] + b2b[i&255];
  float a = alpha[0];
  s = s >= 0.f ? s : a*s;
  x2b[i] = f2b(s);
}

__global__ void reduce_ep3(const float* __restrict__ part, const float* __restrict__ b3b,
                           float* __restrict__ out, int total){
  int i = blockIdx.x*256 + threadIdx.x;
  if (i >= total) return;
  out[i] = part[i] + b3b[i&63];
}

// ---------------- host ------------------------------------------------------
extern "C" void kernel_launch(void* const* d_in, const int* in_sizes, int n_in,
                              void* d_out, int out_size, void* d_ws, size_t ws_size,
                              hipStream_t stream){
  const float* coods = (const float*)d_in[0];
  const float* pe    = (const float*)d_in[1];
  const float* W1w   = (const float*)d_in[2];
  const float* b1w   = (const float*)d_in[3];
  const float* W1b   = (const float*)d_in[4];
  const float* b1b   = (const float*)d_in[5];
  const float* W2w   = (const float*)d_in[6];
  const float* b2w   = (const float*)d_in[7];
  const float* W2b   = (const float*)d_in[8];
  const float* b2b   = (const float*)d_in[9];
  const float* W3w   = (const float*)d_in[10];
  const float* b3w   = (const float*)d_in[11];
  const float* W3b   = (const float*)d_in[12];
  const float* b3b   = (const float*)d_in[13];
  const float* alpha = (const float*)d_in[14];
  float* out = (float*)d_out;

  char* ws = (char*)d_ws;
  size_t off = 0;
  auto alloc = [&](size_t bytes)->void*{ void* p = ws + off; off += (bytes + 255) & ~(size_t)255; return p; };
  u16*   B2   = (u16*)  alloc(1032ull*256*128);   // 32.25 MB
  u16*   B3   = (u16*)  alloc(1032ull*64*128);    //  8.06 MB
  u16*   B1   = (u16*)  alloc(12ull*256*128);     //  0.38 MB
  u16*   peb  = (u16*)  alloc(4096ull*256*2);
  u16*   x1b  = (u16*)  alloc(4096ull*256*2);
  u16*   x2b  = (u16*)  alloc(4096ull*256*2);
  float* part = (float*)alloc(4096ull*256*4);     // 4 MB atomic accumulator
  if (ws_size < off) return;

  // --- pack weights ---
  pack_rowsrc<<<2097152/256, 256, 0, stream>>>(W2w, B2, 8, 256, 256, 2097152);
  pack_colsrc<<<8192/256,    256, 0, stream>>>(b2w, B2 + 1024ull*16384, 8, 8192);
  pack_rowsrc<<<8192/256,    256, 0, stream>>>(W2b, B2 + 1028ull*16384, 8, 256, 0, 8192);
  pack_rowsrc<<<524288/256,  256, 0, stream>>>(W3w, B3, 6, 256, 64, 524288);
  pack_colsrc<<<2048/256,    256, 0, stream>>>(b3w, B3 + 1024ull*4096, 6, 2048);
  pack_rowsrc<<<2048/256,    256, 0, stream>>>(W3b, B3 + 1028ull*4096, 6, 256, 0, 2048);
  pack_rowsrc<<<16384/256,   256, 0, stream>>>(W1w, B1, 8, 256, 256, 16384);
  pack_rowsrc<<<8192/256,    256, 0, stream>>>(W1b, B1 + 8ull*16384, 8, 256, 0, 8192);
  cvt_bf16<<<262144/256, 256, 0, stream>>>(pe, peb, 262144);

  // --- layer 1 (old path, K=12 tiles) ---
  hipMemsetAsync(part, 0, 4096ull*256*4, stream);
  gemm_meta<64,256,512,4,0,4,12,0><<<256, 512, 0, stream>>>(B1, peb, nullptr, coods, part);
  reduce_ep1<<<1048576/256, 256, 0, stream>>>(part, coods, b1w, b1b, alpha, x1b, 1048576);

  // --- layer 2: grouped v3 (BN=128, 80KB LDS -> 2 blocks/CU, grid 512) ---
  hipMemsetAsync(part, 0, 4096ull*256*4, stream);
  gemm_grp3<64,128,256,256,2,2,2><<<512, 256, 0, stream>>>(B2, peb, x1b, part);
  gemm_meta<64,256,512,4,1,4,8,1024><<<256, 512, 0, stream>>>(B2, peb, x1b, nullptr, part);
  reduce_ep2<<<1048576/256, 256, 0, stream>>>(part, b2b, alpha, x2b, 1048576);

  // --- layer 3: grouped v3 (36KB LDS, grid 1024 -> 4 blocks/CU) ---
  hipMemsetAsync(part, 0, 4096ull*64*4, stream);
  gemm_grp3<64,64,64,256,1,8,2><<<1024, 256, 0, stream>>>(B3, peb, x2b, part);
  gemm_meta<64,64,256,2,1,4,8,1024><<<256, 256, 0, stream>>>(B3, peb, x2b, nullptr, part);
  reduce_ep3<<<262144/256, 256, 0, stream>>>(part, b3b, out, 262144);
}